// Round 1
// baseline (718.521 us; speedup 1.0000x reference)
//
#include <hip/hip_runtime.h>

#define NSTEPS 20
#define BATCH 64
#define D_IN 16384
#define KNN 25
#define BETA 0.85

#define D0 8192
#define D1 4096
#define D2 2048

// ---------------------------------------------------------------------------
// Transpose x (B, T, D_IN) f32 -> xT (T, D_IN, B) f32 so that layer-0 gathers
// (uniform column index per wave, lane = batch) are 256B coalesced loads.
// ---------------------------------------------------------------------------
__global__ void __launch_bounds__(256) transpose_x_kernel(
    const float* __restrict__ x, float* __restrict__ xT) {
  __shared__ float tile[64][65];
  const int t = blockIdx.y;
  const int d0 = blockIdx.x * 64;
  {
    const int dd = threadIdx.x & 63;
    const int bg = threadIdx.x >> 6;
#pragma unroll
    for (int i = 0; i < 16; ++i) {
      const int b = bg * 16 + i;
      tile[b][dd] = x[((size_t)b * NSTEPS + t) * D_IN + d0 + dd];
    }
  }
  __syncthreads();
  {
    const int b = threadIdx.x & 63;
    const int dg = threadIdx.x >> 6;
#pragma unroll
    for (int i = 0; i < 16; ++i) {
      const int d = dg * 16 + i;
      xT[((size_t)t * D_IN + d0 + d) * BATCH + b] = tile[b][d];
    }
  }
}

// ---------------------------------------------------------------------------
// One LIF layer, ALL timesteps in one launch.
//  - CARRY=true : per-thread sequential scan over t (layers 0,1)
//  - CARRY=false: t comes from blockIdx.y, stateless (layer 2: mem_prev==0)
//  - IS_U8=true : source is packed 0/1 spikes (u8), else f32.
// Generic strides so the same kernel serves transposed-scratch or direct
// (fallback) layouts:  src[t*st_t + lane*st_b + idx*st_idx].
// Block: 512 threads = 8 waves; block owns 16 d-values x all 64 b.
// lane = batch (coalesced gathers); output writes go through an LDS
// transpose so stores to the (T,B,D) outputs are 64B-line coalesced.
// f64 accumulation/recurrence to match the numpy reference's spike decisions.
// ---------------------------------------------------------------------------
template <bool IS_U8, bool CARRY>
__global__ void __launch_bounds__(512) layer_scan_kernel(
    const void* __restrict__ src, size_t st_t, size_t st_b, size_t st_idx,
    const float* __restrict__ W, const float* __restrict__ bias,
    const int* __restrict__ knn, const float* __restrict__ thr, int D,
    float* __restrict__ mem_rec, float* __restrict__ spk_rec,
    unsigned char* __restrict__ spkT) {
  __shared__ float s_mem[16][68];
  __shared__ float s_spk[16][68];
  const int d0 = blockIdx.x * 16;
  const int lane = threadIdx.x & 63;  // batch index
  const int wv = threadIdx.x >> 6;    // 0..7
  const int dbase = d0 + wv * 2;

  double mem[2] = {0.0, 0.0};
  double thrv[2], bsv[2];
#pragma unroll
  for (int j = 0; j < 2; ++j) {
    thrv[j] = (double)thr[dbase + j];
    bsv[j] = (double)bias[dbase + j];
  }

  const int t_lo = CARRY ? 0 : (int)blockIdx.y;
  const int t_hi = CARRY ? NSTEPS : (int)blockIdx.y + 1;

  for (int t = t_lo; t < t_hi; ++t) {
#pragma unroll
    for (int j = 0; j < 2; ++j) {
      const int d = dbase + j;
      const int* kp = knn + (size_t)d * KNN;
      const float* wp = W + (size_t)d * KNN;
      const size_t base = (size_t)t * st_t + (size_t)lane * st_b;
      double cur = bsv[j];
#pragma unroll
      for (int k = 0; k < KNN; ++k) {
        const int idx = kp[k];
        if (IS_U8) {
          const unsigned char s =
              ((const unsigned char*)src)[base + (size_t)idx * st_idx];
          cur += (double)wp[k] * (double)s;
        } else {
          const float g = ((const float*)src)[base + (size_t)idx * st_idx];
          cur += (double)wp[k] * (double)g;
        }
      }
      double m = CARRY ? mem[j] : 0.0;
      const double reset = (m > thrv[j]) ? thrv[j] : 0.0;
      m = BETA * m + cur - reset;
      mem[j] = m;
      const float spk = (m > thrv[j]) ? 1.0f : 0.0f;
      s_mem[wv * 2 + j][lane] = (float)m;
      s_spk[wv * 2 + j][lane] = spk;
      if (spkT) spkT[((size_t)t * D + d) * BATCH + lane] = (unsigned char)spk;
    }
    __syncthreads();
    {
      const int dd = threadIdx.x & 15;
      const int bq = threadIdx.x >> 4;  // 0..31
#pragma unroll
      for (int i = 0; i < 2; ++i) {
        const int b = bq + 32 * i;
        const size_t o = ((size_t)t * BATCH + b) * D + d0 + dd;
        mem_rec[o] = s_mem[dd][b];
        spk_rec[o] = s_spk[dd][b];
      }
    }
    __syncthreads();
  }
}

// ---------------------------------------------------------------------------
// angles = mem2[T-1] @ Wfc.T + bfc   (64x2048)·(2x2048)^T, tiny
// ---------------------------------------------------------------------------
__global__ void __launch_bounds__(64) fc_kernel(
    const float* __restrict__ mem2, const float* __restrict__ Wfc,
    const float* __restrict__ bfc, float* __restrict__ angles) {
  const int b = blockIdx.x;
  const float* h = mem2 + ((size_t)(NSTEPS - 1) * BATCH + b) * D2;
  double a0 = 0.0, a1 = 0.0;
  for (int d = threadIdx.x; d < D2; d += 64) {
    const double m = (double)h[d];
    a0 += m * (double)Wfc[d];
    a1 += m * (double)Wfc[D2 + d];
  }
#pragma unroll
  for (int off = 32; off > 0; off >>= 1) {
    a0 += __shfl_down(a0, off);
    a1 += __shfl_down(a1, off);
  }
  if (threadIdx.x == 0) {
    angles[(size_t)b * 2 + 0] = (float)(a0 + (double)bfc[0]);
    angles[(size_t)b * 2 + 1] = (float)(a1 + (double)bfc[1]);
  }
}

extern "C" void kernel_launch(void* const* d_in, const int* in_sizes, int n_in,
                              void* d_out, int out_size, void* d_ws,
                              size_t ws_size, hipStream_t stream) {
  const float* x = (const float*)d_in[0];
  const float* W0 = (const float*)d_in[1];
  const float* b0 = (const float*)d_in[2];
  const int* knn0 = (const int*)d_in[3];
  const float* thr0 = (const float*)d_in[4];
  const float* W1 = (const float*)d_in[5];
  const float* b1 = (const float*)d_in[6];
  const int* knn1 = (const int*)d_in[7];
  const float* thr1 = (const float*)d_in[8];
  const float* W2 = (const float*)d_in[9];
  const float* b2 = (const float*)d_in[10];
  const int* knn2 = (const int*)d_in[11];
  const float* thr2 = (const float*)d_in[12];
  const float* Wfc = (const float*)d_in[13];
  const float* bfc = (const float*)d_in[14];

  float* out = (float*)d_out;
  float* mem_rec0 = out;
  float* mem_rec1 = mem_rec0 + (size_t)NSTEPS * BATCH * D0;
  float* mem_rec2 = mem_rec1 + (size_t)NSTEPS * BATCH * D1;
  float* spk_rec0 = mem_rec2 + (size_t)NSTEPS * BATCH * D2;
  float* spk_rec1 = spk_rec0 + (size_t)NSTEPS * BATCH * D0;
  float* spk_rec2 = spk_rec1 + (size_t)NSTEPS * BATCH * D1;
  float* angles = spk_rec2 + (size_t)NSTEPS * BATCH * D2;

  const size_t xT_bytes = (size_t)NSTEPS * D_IN * BATCH * sizeof(float);
  const size_t s0_bytes = (size_t)NSTEPS * D0 * BATCH;  // u8 spikes
  const size_t s1_bytes = (size_t)NSTEPS * D1 * BATCH;

  const bool planA = ws_size >= xT_bytes + s0_bytes + s1_bytes;
  const bool planB = !planA && ws_size >= s0_bytes + s1_bytes;

  const dim3 blk(512);

  if (planA) {
    float* xT = (float*)d_ws;
    unsigned char* spk0T = (unsigned char*)d_ws + xT_bytes;
    unsigned char* spk1T = spk0T + s0_bytes;

    transpose_x_kernel<<<dim3(D_IN / 64, NSTEPS), 256, 0, stream>>>(x, xT);
    layer_scan_kernel<false, true><<<dim3(D0 / 16), blk, 0, stream>>>(
        xT, (size_t)D_IN * BATCH, 1, BATCH, W0, b0, knn0, thr0, D0, mem_rec0,
        spk_rec0, spk0T);
    layer_scan_kernel<true, true><<<dim3(D1 / 16), blk, 0, stream>>>(
        spk0T, (size_t)D0 * BATCH, 1, BATCH, W1, b1, knn1, thr1, D1, mem_rec1,
        spk_rec1, spk1T);
    layer_scan_kernel<true, false><<<dim3(D2 / 16, NSTEPS), blk, 0, stream>>>(
        spk1T, (size_t)D1 * BATCH, 1, BATCH, W2, b2, knn2, thr2, D2, mem_rec2,
        spk_rec2, nullptr);
  } else if (planB) {
    unsigned char* spk0T = (unsigned char*)d_ws;
    unsigned char* spk1T = spk0T + s0_bytes;

    // layer 0 gathers straight from x (B,T,D): strided lanes, L3-served
    layer_scan_kernel<false, true><<<dim3(D0 / 16), blk, 0, stream>>>(
        x, (size_t)D_IN, (size_t)NSTEPS * D_IN, 1, W0, b0, knn0, thr0, D0,
        mem_rec0, spk_rec0, spk0T);
    layer_scan_kernel<true, true><<<dim3(D1 / 16), blk, 0, stream>>>(
        spk0T, (size_t)D0 * BATCH, 1, BATCH, W1, b1, knn1, thr1, D1, mem_rec1,
        spk_rec1, spk1T);
    layer_scan_kernel<true, false><<<dim3(D2 / 16, NSTEPS), blk, 0, stream>>>(
        spk1T, (size_t)D1 * BATCH, 1, BATCH, W2, b2, knn2, thr2, D2, mem_rec2,
        spk_rec2, nullptr);
  } else {
    // No scratch: gather spikes back out of d_out (f32, (T,B,D) layout)
    layer_scan_kernel<false, true><<<dim3(D0 / 16), blk, 0, stream>>>(
        x, (size_t)D_IN, (size_t)NSTEPS * D_IN, 1, W0, b0, knn0, thr0, D0,
        mem_rec0, spk_rec0, nullptr);
    layer_scan_kernel<false, true><<<dim3(D1 / 16), blk, 0, stream>>>(
        spk_rec0, (size_t)BATCH * D0, (size_t)D0, 1, W1, b1, knn1, thr1, D1,
        mem_rec1, spk_rec1, nullptr);
    layer_scan_kernel<false, false><<<dim3(D2 / 16, NSTEPS), blk, 0, stream>>>(
        spk_rec1, (size_t)BATCH * D1, (size_t)D1, 1, W2, b2, knn2, thr2, D2,
        mem_rec2, spk_rec2, nullptr);
  }

  fc_kernel<<<dim3(BATCH), 64, 0, stream>>>(mem_rec2, Wfc, bfc, angles);
}

// Round 2
// 240.613 us; speedup vs baseline: 2.9862x; 2.9862x over previous
//
#include <hip/hip_runtime.h>

#define NSTEPS 20
#define BATCH 64
#define D_IN 16384
#define KNN 25
#define BETA 0.85

#define D0 8192
#define D1 4096
#define D2 2048

// Number of t-groups of 8 for the XCD swizzle (ceil(20/8)*8 = 24)
#define NRT 24

// ---------------------------------------------------------------------------
// Transpose x (B, T, D_IN) f32 -> xT (T, D_IN, B) f32 so that layer-0 gathers
// (uniform column index per wave, lane = batch) are 256B coalesced loads.
// ---------------------------------------------------------------------------
__global__ void __launch_bounds__(256) transpose_x_kernel(
    const float* __restrict__ x, float* __restrict__ xT) {
  __shared__ float tile[64][65];
  const int t = blockIdx.y;
  const int d0 = blockIdx.x * 64;
  {
    const int dd = threadIdx.x & 63;
    const int bg = threadIdx.x >> 6;
#pragma unroll
    for (int i = 0; i < 16; ++i) {
      const int b = bg * 16 + i;
      tile[b][dd] = x[((size_t)b * NSTEPS + t) * D_IN + d0 + dd];
    }
  }
  __syncthreads();
  {
    const int b = threadIdx.x & 63;
    const int dg = threadIdx.x >> 6;
#pragma unroll
    for (int i = 0; i < 16; ++i) {
      const int d = dg * 16 + i;
      xT[((size_t)t * D_IN + d0 + d) * BATCH + b] = tile[b][d];
    }
  }
}

// ---------------------------------------------------------------------------
// t-PARALLEL current kernel: cur[t, dl, b] (f64) for one d-chunk of a layer.
// Grid: 24 * (dn/16) blocks, decoded so that all blocks of a given t land on
// the same XCD (assuming hw round-robin bid%8 -> XCD): bid%8 == t%8.
// Block: 512 thr = 8 waves; wave handles 2 d values x 64 b (lane = batch).
// f64 FMA chain in identical k-order to the verified round-1 kernel.
// ---------------------------------------------------------------------------
template <bool IS_U8>
__global__ void __launch_bounds__(512) cur_kernel(
    const void* __restrict__ src, size_t st_t, const float* __restrict__ W,
    const float* __restrict__ bias, const int* __restrict__ knn, int dn,
    int dchunk0, double* __restrict__ curbuf) {
  const int nb_d = dn >> 4;
  const int g = blockIdx.x & 7;
  const int q = blockIdx.x >> 3;
  const int r = q / nb_d;
  const int i = q - r * nb_d;
  const int t = r * 8 + g;
  if (t >= NSTEPS) return;

  const int lane = threadIdx.x & 63;
  const int wv = threadIdx.x >> 6;
  const int dl0 = i * 16 + wv * 2;  // local d within chunk (2 per wave)

#pragma unroll
  for (int j = 0; j < 2; ++j) {
    const int dl = dl0 + j;
    const int dg = __builtin_amdgcn_readfirstlane(dchunk0 + dl);
    const int* kp = knn + (size_t)dg * KNN;
    const float* wp = W + (size_t)dg * KNN;
    double cur = (double)bias[dg];
    if (IS_U8) {
      const unsigned char* sp =
          (const unsigned char*)src + (size_t)t * st_t + lane;
#pragma unroll
      for (int k = 0; k < KNN; ++k) {
        const int idx = kp[k];
        cur += (double)wp[k] * (double)sp[(size_t)idx * BATCH];
      }
    } else {
      const float* sp = (const float*)src + (size_t)t * st_t + lane;
#pragma unroll
      for (int k = 0; k < KNN; ++k) {
        const int idx = kp[k];
        cur += (double)wp[k] * (double)sp[(size_t)idx * BATCH];
      }
    }
    curbuf[((size_t)t * dn + dl) * BATCH + lane] = cur;
  }
}

// ---------------------------------------------------------------------------
// Recurrence scan over t for one d-chunk: reads f64 cur, runs the LIF update
// (identical op order to round-1), writes mem/spk recs (T,B,D) via LDS
// transpose and packed u8 spikes (T,D,B).
// Block: 512 thr covers 16 local d x 64 b.
// ---------------------------------------------------------------------------
__global__ void __launch_bounds__(512) scan_kernel(
    const double* __restrict__ curbuf, int dn, int dchunk0, int D,
    const float* __restrict__ thr, float* __restrict__ mem_rec,
    float* __restrict__ spk_rec, unsigned char* __restrict__ spkT) {
  __shared__ float s_mem[16][68];
  __shared__ float s_spk[16][68];
  const int dl0 = blockIdx.x * 16;
  const int lane = threadIdx.x & 63;
  const int wv = threadIdx.x >> 6;
  const int dbase = dl0 + wv * 2;

  double mem[2] = {0.0, 0.0};
  double thrv[2];
#pragma unroll
  for (int j = 0; j < 2; ++j) thrv[j] = (double)thr[dchunk0 + dbase + j];

  for (int t = 0; t < NSTEPS; ++t) {
#pragma unroll
    for (int j = 0; j < 2; ++j) {
      const int dl = dbase + j;
      const double cur = curbuf[((size_t)t * dn + dl) * BATCH + lane];
      double m = mem[j];
      const double reset = (m > thrv[j]) ? thrv[j] : 0.0;
      m = BETA * m + cur - reset;
      mem[j] = m;
      const float spk = (m > thrv[j]) ? 1.0f : 0.0f;
      s_mem[wv * 2 + j][lane] = (float)m;
      s_spk[wv * 2 + j][lane] = spk;
      if (spkT)
        spkT[((size_t)t * D + dchunk0 + dl) * BATCH + lane] =
            (unsigned char)spk;
    }
    __syncthreads();
    {
      const int dd = threadIdx.x & 15;
      const int bq = threadIdx.x >> 4;  // 0..31
#pragma unroll
      for (int i = 0; i < 2; ++i) {
        const int b = bq + 32 * i;
        const size_t o = ((size_t)t * BATCH + b) * D + dchunk0 + dl0 + dd;
        mem_rec[o] = s_mem[dd][b];
        spk_rec[o] = s_spk[dd][b];
      }
    }
    __syncthreads();
  }
}

// ---------------------------------------------------------------------------
// Fused LIF layer (round-1 structure), kept for layer 2 (stateless,
// t-parallel) and as the fallback when workspace is too small.
// ---------------------------------------------------------------------------
template <bool IS_U8, bool CARRY>
__global__ void __launch_bounds__(512) layer_scan_kernel(
    const void* __restrict__ src, size_t st_t, size_t st_b, size_t st_idx,
    const float* __restrict__ W, const float* __restrict__ bias,
    const int* __restrict__ knn, const float* __restrict__ thr, int D,
    float* __restrict__ mem_rec, float* __restrict__ spk_rec,
    unsigned char* __restrict__ spkT) {
  __shared__ float s_mem[16][68];
  __shared__ float s_spk[16][68];
  const int d0 = blockIdx.x * 16;
  const int lane = threadIdx.x & 63;  // batch index
  const int wv = threadIdx.x >> 6;    // 0..7
  const int dbase = d0 + wv * 2;

  double mem[2] = {0.0, 0.0};
  double thrv[2], bsv[2];
#pragma unroll
  for (int j = 0; j < 2; ++j) {
    thrv[j] = (double)thr[dbase + j];
    bsv[j] = (double)bias[dbase + j];
  }

  const int t_lo = CARRY ? 0 : (int)blockIdx.y;
  const int t_hi = CARRY ? NSTEPS : (int)blockIdx.y + 1;

  for (int t = t_lo; t < t_hi; ++t) {
#pragma unroll
    for (int j = 0; j < 2; ++j) {
      const int d = dbase + j;
      const int* kp = knn + (size_t)d * KNN;
      const float* wp = W + (size_t)d * KNN;
      const size_t base = (size_t)t * st_t + (size_t)lane * st_b;
      double cur = bsv[j];
#pragma unroll
      for (int k = 0; k < KNN; ++k) {
        const int idx = kp[k];
        if (IS_U8) {
          const unsigned char s =
              ((const unsigned char*)src)[base + (size_t)idx * st_idx];
          cur += (double)wp[k] * (double)s;
        } else {
          const float g = ((const float*)src)[base + (size_t)idx * st_idx];
          cur += (double)wp[k] * (double)g;
        }
      }
      double m = CARRY ? mem[j] : 0.0;
      const double reset = (m > thrv[j]) ? thrv[j] : 0.0;
      m = BETA * m + cur - reset;
      mem[j] = m;
      const float spk = (m > thrv[j]) ? 1.0f : 0.0f;
      s_mem[wv * 2 + j][lane] = (float)m;
      s_spk[wv * 2 + j][lane] = spk;
      if (spkT) spkT[((size_t)t * D + d) * BATCH + lane] = (unsigned char)spk;
    }
    __syncthreads();
    {
      const int dd = threadIdx.x & 15;
      const int bq = threadIdx.x >> 4;  // 0..31
#pragma unroll
      for (int i = 0; i < 2; ++i) {
        const int b = bq + 32 * i;
        const size_t o = ((size_t)t * BATCH + b) * D + d0 + dd;
        mem_rec[o] = s_mem[dd][b];
        spk_rec[o] = s_spk[dd][b];
      }
    }
    __syncthreads();
  }
}

// ---------------------------------------------------------------------------
// angles = mem2[T-1] @ Wfc.T + bfc   (64x2048)·(2x2048)^T, tiny
// ---------------------------------------------------------------------------
__global__ void __launch_bounds__(64) fc_kernel(
    const float* __restrict__ mem2, const float* __restrict__ Wfc,
    const float* __restrict__ bfc, float* __restrict__ angles) {
  const int b = blockIdx.x;
  const float* h = mem2 + ((size_t)(NSTEPS - 1) * BATCH + b) * D2;
  double a0 = 0.0, a1 = 0.0;
  for (int d = threadIdx.x; d < D2; d += 64) {
    const double m = (double)h[d];
    a0 += m * (double)Wfc[d];
    a1 += m * (double)Wfc[D2 + d];
  }
#pragma unroll
  for (int off = 32; off > 0; off >>= 1) {
    a0 += __shfl_down(a0, off);
    a1 += __shfl_down(a1, off);
  }
  if (threadIdx.x == 0) {
    angles[(size_t)b * 2 + 0] = (float)(a0 + (double)bfc[0]);
    angles[(size_t)b * 2 + 1] = (float)(a1 + (double)bfc[1]);
  }
}

extern "C" void kernel_launch(void* const* d_in, const int* in_sizes, int n_in,
                              void* d_out, int out_size, void* d_ws,
                              size_t ws_size, hipStream_t stream) {
  const float* x = (const float*)d_in[0];
  const float* W0 = (const float*)d_in[1];
  const float* b0 = (const float*)d_in[2];
  const int* knn0 = (const int*)d_in[3];
  const float* thr0 = (const float*)d_in[4];
  const float* W1 = (const float*)d_in[5];
  const float* b1 = (const float*)d_in[6];
  const int* knn1 = (const int*)d_in[7];
  const float* thr1 = (const float*)d_in[8];
  const float* W2 = (const float*)d_in[9];
  const float* b2 = (const float*)d_in[10];
  const int* knn2 = (const int*)d_in[11];
  const float* thr2 = (const float*)d_in[12];
  const float* Wfc = (const float*)d_in[13];
  const float* bfc = (const float*)d_in[14];

  float* out = (float*)d_out;
  float* mem_rec0 = out;
  float* mem_rec1 = mem_rec0 + (size_t)NSTEPS * BATCH * D0;
  float* mem_rec2 = mem_rec1 + (size_t)NSTEPS * BATCH * D1;
  float* spk_rec0 = mem_rec2 + (size_t)NSTEPS * BATCH * D2;
  float* spk_rec1 = spk_rec0 + (size_t)NSTEPS * BATCH * D0;
  float* spk_rec2 = spk_rec1 + (size_t)NSTEPS * BATCH * D1;
  float* angles = spk_rec2 + (size_t)NSTEPS * BATCH * D2;

  const size_t xT_bytes = (size_t)NSTEPS * D_IN * BATCH * sizeof(float);
  const size_t s0_bytes = (size_t)NSTEPS * D0 * BATCH;  // u8 spikes
  const size_t s1_bytes = (size_t)NSTEPS * D1 * BATCH;
  const size_t base_bytes = xT_bytes + s0_bytes + s1_bytes;

  const bool planA = ws_size >= base_bytes;
  const bool planB = !planA && ws_size >= s0_bytes + s1_bytes;

  // f64 cur chunk size (in d) that fits in leftover workspace
  size_t leftover = (ws_size > base_bytes) ? ws_size - base_bytes : 0;
  int Dc = (int)((leftover / ((size_t)NSTEPS * BATCH * 8)) & ~(size_t)15);
  if (Dc > D0) Dc = D0;
  const bool planT = planA && Dc >= 512;

  const dim3 blk(512);

  if (planT) {
    float* xT = (float*)d_ws;
    unsigned char* spk0T = (unsigned char*)d_ws + xT_bytes;
    unsigned char* spk1T = spk0T + s0_bytes;
    double* curbuf = (double*)((char*)d_ws + base_bytes);

    transpose_x_kernel<<<dim3(D_IN / 64, NSTEPS), 256, 0, stream>>>(x, xT);

    // layer 0: t-parallel currents (chunked over d) + scan
    for (int c0 = 0; c0 < D0; c0 += Dc) {
      const int dn = (D0 - c0 < Dc) ? (D0 - c0) : Dc;
      cur_kernel<false><<<dim3(NRT * (dn / 16)), blk, 0, stream>>>(
          xT, (size_t)D_IN * BATCH, W0, b0, knn0, dn, c0, curbuf);
      scan_kernel<<<dim3(dn / 16), blk, 0, stream>>>(
          curbuf, dn, c0, D0, thr0, mem_rec0, spk_rec0, spk0T);
    }
    // layer 1: gathers from u8 spikes
    for (int c0 = 0; c0 < D1; c0 += Dc) {
      const int dn = (D1 - c0 < Dc) ? (D1 - c0) : Dc;
      cur_kernel<true><<<dim3(NRT * (dn / 16)), blk, 0, stream>>>(
          spk0T, (size_t)D0 * BATCH, W1, b1, knn1, dn, c0, curbuf);
      scan_kernel<<<dim3(dn / 16), blk, 0, stream>>>(
          curbuf, dn, c0, D1, thr1, mem_rec1, spk_rec1, spk1T);
    }
    // layer 2: stateless, already t-parallel fused
    layer_scan_kernel<true, false><<<dim3(D2 / 16, NSTEPS), blk, 0, stream>>>(
        spk1T, (size_t)D1 * BATCH, 1, BATCH, W2, b2, knn2, thr2, D2, mem_rec2,
        spk_rec2, nullptr);
  } else if (planA) {
    float* xT = (float*)d_ws;
    unsigned char* spk0T = (unsigned char*)d_ws + xT_bytes;
    unsigned char* spk1T = spk0T + s0_bytes;

    transpose_x_kernel<<<dim3(D_IN / 64, NSTEPS), 256, 0, stream>>>(x, xT);
    layer_scan_kernel<false, true><<<dim3(D0 / 16), blk, 0, stream>>>(
        xT, (size_t)D_IN * BATCH, 1, BATCH, W0, b0, knn0, thr0, D0, mem_rec0,
        spk_rec0, spk0T);
    layer_scan_kernel<true, true><<<dim3(D1 / 16), blk, 0, stream>>>(
        spk0T, (size_t)D0 * BATCH, 1, BATCH, W1, b1, knn1, thr1, D1, mem_rec1,
        spk_rec1, spk1T);
    layer_scan_kernel<true, false><<<dim3(D2 / 16, NSTEPS), blk, 0, stream>>>(
        spk1T, (size_t)D1 * BATCH, 1, BATCH, W2, b2, knn2, thr2, D2, mem_rec2,
        spk_rec2, nullptr);
  } else if (planB) {
    unsigned char* spk0T = (unsigned char*)d_ws;
    unsigned char* spk1T = spk0T + s0_bytes;

    layer_scan_kernel<false, true><<<dim3(D0 / 16), blk, 0, stream>>>(
        x, (size_t)D_IN, (size_t)NSTEPS * D_IN, 1, W0, b0, knn0, thr0, D0,
        mem_rec0, spk_rec0, spk0T);
    layer_scan_kernel<true, true><<<dim3(D1 / 16), blk, 0, stream>>>(
        spk0T, (size_t)D0 * BATCH, 1, BATCH, W1, b1, knn1, thr1, D1, mem_rec1,
        spk_rec1, spk1T);
    layer_scan_kernel<true, false><<<dim3(D2 / 16, NSTEPS), blk, 0, stream>>>(
        spk1T, (size_t)D1 * BATCH, 1, BATCH, W2, b2, knn2, thr2, D2, mem_rec2,
        spk_rec2, nullptr);
  } else {
    layer_scan_kernel<false, true><<<dim3(D0 / 16), blk, 0, stream>>>(
        x, (size_t)D_IN, (size_t)NSTEPS * D_IN, 1, W0, b0, knn0, thr0, D0,
        mem_rec0, spk_rec0, nullptr);
    layer_scan_kernel<false, true><<<dim3(D1 / 16), blk, 0, stream>>>(
        spk_rec0, (size_t)BATCH * D0, (size_t)D0, 1, W1, b1, knn1, thr1, D1,
        mem_rec1, spk_rec1, nullptr);
    layer_scan_kernel<false, false><<<dim3(D2 / 16, NSTEPS), blk, 0, stream>>>(
        spk_rec1, (size_t)BATCH * D1, (size_t)D1, 1, W2, b2, knn2, thr2, D2,
        mem_rec2, spk_rec2, nullptr);
  }

  fc_kernel<<<dim3(BATCH), 64, 0, stream>>>(mem_rec2, Wfc, bfc, angles);
}